// Round 2
// baseline (344.330 us; speedup 1.0000x reference)
//
#include <hip/hip_runtime.h>

#define Q 20
#define RSTRIDE 21          // odd stride: gcd(21,32)=1 -> lanes spread over all 32 banks, 2-way max (free)
#define BLOCK 256
#define BLOCKS_PER_ROW 28   // 64 rows * 28 = 1792 = 7 blocks/CU * 256 CUs (7/CU is the LDS limit at 21.6KB)
#define L_FIXED 1000000

// Per-block partial histograms: part[block][q], block = row*BLOCKS_PER_ROW + cb.
__global__ __launch_bounds__(BLOCK) void hist_kernel(const float* __restrict__ x,
                                                     unsigned int* __restrict__ part) {
    __shared__ unsigned int sh[BLOCK * RSTRIDE];   // thread-private replicas: no same-address contention ever
    __shared__ unsigned int fin[Q];

    #pragma unroll
    for (int i = 0; i < RSTRIDE; ++i) sh[threadIdx.x * RSTRIDE + i] = 0u;
    if (threadIdx.x < Q) fin[threadIdx.x] = 0u;
    __syncthreads();

    const int row = blockIdx.x / BLOCKS_PER_ROW;
    const int cb  = blockIdx.x % BLOCKS_PER_ROW;
    const float4* __restrict__ rowp = (const float4*)(x + (long long)row * L_FIXED);
    const int nvec = L_FIXED >> 2;                 // 250000 float4 per row
    const int half = nvec >> 1;                    // 125000
    const int stride = BLOCKS_PER_ROW * BLOCK;     // 7168
    unsigned int* myrep = sh + threadIdx.x * RSTRIDE;

    // Two independent halves per iteration: 2 loads in flight, 8 elements/iter.
    for (int i = cb * BLOCK + threadIdx.x; i < half; i += stride) {
        float4 v0 = rowp[i];
        float4 v1 = rowp[i + half];
        // x in [0,1): (int)(x*20.0f) == floor(x*20) and is provably <= 19 (no min needed).
        int a0 = (int)(v0.x * 20.0f), a1 = (int)(v0.y * 20.0f);
        int a2 = (int)(v0.z * 20.0f), a3 = (int)(v0.w * 20.0f);
        int b0 = (int)(v1.x * 20.0f), b1 = (int)(v1.y * 20.0f);
        int b2 = (int)(v1.z * 20.0f), b3 = (int)(v1.w * 20.0f);
        atomicAdd(&myrep[a0], 1u); atomicAdd(&myrep[a1], 1u);
        atomicAdd(&myrep[a2], 1u); atomicAdd(&myrep[a3], 1u);
        atomicAdd(&myrep[b0], 1u); atomicAdd(&myrep[b1], 1u);
        atomicAdd(&myrep[b2], 1u); atomicAdd(&myrep[b3], 1u);
    }
    __syncthreads();

    // Reduce 256 replicas -> 20 bins: 160 threads, q = t>>3, group g = t&7 sums 32 replicas.
    if (threadIdx.x < Q * 8) {
        int q = threadIdx.x >> 3;
        int g = threadIdx.x & 7;
        unsigned int s = 0;
        #pragma unroll
        for (int r = 0; r < 32; ++r) s += sh[(g * 32 + r) * RSTRIDE + q];
        atomicAdd(&fin[q], s);
    }
    __syncthreads();
    if (threadIdx.x < Q) part[blockIdx.x * Q + threadIdx.x] = fin[threadIdx.x];
}

// Single block: sum 28 partials per (row,bin), entropy, reduce, write scalar.
__global__ __launch_bounds__(1024) void entropy_kernel(const unsigned int* __restrict__ part,
                                                       float* __restrict__ out,
                                                       int nrows, float invL) {
    float s = 0.0f;
    const int npairs = nrows * Q;                  // 1280
    for (int p = threadIdx.x; p < npairs; p += 1024) {
        int row = p / Q;
        int q   = p % Q;
        unsigned int c = 0;
        #pragma unroll
        for (int cb = 0; cb < BLOCKS_PER_ROW; ++cb)
            c += part[(row * BLOCKS_PER_ROW + cb) * Q + q];
        if (c > 0u) {
            float pr = (float)c * invL;
            s -= pr * __log2f(pr);
        }
    }
    #pragma unroll
    for (int off = 32; off > 0; off >>= 1) s += __shfl_down(s, off, 64);
    __shared__ float wsum[1024 / 64];
    int wid  = threadIdx.x >> 6;
    int lane = threadIdx.x & 63;
    if (lane == 0) wsum[wid] = s;
    __syncthreads();
    if (threadIdx.x == 0) {
        float t = 0.0f;
        #pragma unroll
        for (int w = 0; w < 1024 / 64; ++w) t += wsum[w];
        out[0] = t;
    }
}

extern "C" void kernel_launch(void* const* d_in, const int* in_sizes, int n_in,
                              void* d_out, int out_size, void* d_ws, size_t ws_size,
                              hipStream_t stream) {
    const float* x = (const float*)d_in[0];
    float* out = (float*)d_out;
    unsigned int* part = (unsigned int*)d_ws;      // 1792 * 20 u32 = 143 KB

    const int B = in_sizes[0] / L_FIXED;           // 64

    hist_kernel<<<B * BLOCKS_PER_ROW, BLOCK, 0, stream>>>(x, part);
    entropy_kernel<<<1, 1024, 0, stream>>>(part, out, B, 1.0f / (float)L_FIXED);
}